// Round 1
// baseline (473.610 us; speedup 1.0000x reference)
//
#include <hip/hip_runtime.h>
#include <hip/hip_bf16.h>
#include <stdint.h>

#define D_DIM 2048
#define B_TOK 4096
#define COEF (2.0f / 8388608.0f)   // 2/(B*D)

typedef __bf16 bf16x8 __attribute__((ext_vector_type(8)));
typedef float  f32x4  __attribute__((ext_vector_type(4)));

__device__ __forceinline__ unsigned short f2bf(float f) {
  return __builtin_bit_cast(unsigned short, (__bf16)f);
}
__device__ __forceinline__ float bf2f(unsigned short u) {
  return (float)__builtin_bit_cast(__bf16, u);
}

// async global->LDS, 16B per lane; LDS dest = wave-uniform base + lane*16
__device__ __forceinline__ void async16(const void* g, void* l) {
  __builtin_amdgcn_global_load_lds(
      (__attribute__((address_space(1))) void*)(g),
      (__attribute__((address_space(3))) void*)(l),
      16, 0, 0);
}

// ---------------------------------------------------------------------------
// Core bt-GEMM: C[128x128] tile, A[M,K] row-major, B[N,K] row-major, lda=ldb=K.
// BK=64, 4 waves (2x2), each wave 64x64 via 4x4 mfma_f32_16x16x32_bf16.
// LDS chunk swizzle: LDS(row, c) holds global chunk (row, c ^ (row&7)) so that
// quad fragment reads are 2-way bank aliased (free) instead of 16-way.
// ---------------------------------------------------------------------------
__device__ __forceinline__ void gemm_core(const unsigned short* __restrict__ Ablk,
                                          const unsigned short* __restrict__ Bblk,
                                          const int K,
                                          unsigned short* As, unsigned short* Bs,
                                          f32x4 acc[4][4]) {
  const int tid  = threadIdx.x;
  const int lane = tid & 63;
  const int wv   = tid >> 6;
  const int wm   = wv & 1, wn = wv >> 1;
  const int t    = lane & 15;
  const int quad = lane >> 4;
  const int lrow = lane >> 3;      // 0..7 within an 8-row staging segment
  const int kq   = lane & 7;       // 16B chunk within a 64-col row
  const int kqs  = kq ^ lrow;      // swizzled source chunk (row&7 == lrow)

  const int nk = K >> 6;
  for (int kt = 0; kt < nk; ++kt) {
    const int k0 = kt << 6;
#pragma unroll
    for (int l = 0; l < 4; ++l) {
      const int seg = wv * 4 + l;           // 16 segments of 8 rows
      const int r   = seg * 8 + lrow;
      const size_t goff = (size_t)r * K + k0 + kqs * 8;
      async16(Ablk + goff, As + seg * 512);
      async16(Bblk + goff, Bs + seg * 512);
    }
    __syncthreads();                         // drains vmcnt, staging visible
#pragma unroll
    for (int s = 0; s < 2; ++s) {            // two K=32 MFMA steps per BK=64
      bf16x8 af[4], bfr[4];
#pragma unroll
      for (int i = 0; i < 4; ++i) {
        const int rm = wm * 64 + i * 16 + t;
        af[i]  = *(const bf16x8*)(As + rm * 64 + (((s << 2) + quad) ^ (rm & 7)) * 8);
        const int rn = wn * 64 + i * 16 + t;
        bfr[i] = *(const bf16x8*)(Bs + rn * 64 + (((s << 2) + quad) ^ (rn & 7)) * 8);
      }
#pragma unroll
      for (int i = 0; i < 4; ++i)
#pragma unroll
        for (int j = 0; j < 4; ++j)
          acc[i][j] = __builtin_amdgcn_mfma_f32_16x16x32_bf16(af[i], bfr[j], acc[i][j], 0, 0, 0);
    }
    __syncthreads();                         // all reads done before next stage
  }
}

#define GEMM_PROLOGUE(AP, BP, KK)                                              \
  __shared__ __align__(16) unsigned short As[128 * 64];                        \
  __shared__ __align__(16) unsigned short Bs[128 * 64];                        \
  const int K = (KK);                                                          \
  const unsigned short* Ablk = (AP) + (size_t)blockIdx.y * 128 * K;            \
  const unsigned short* Bblk = (BP) + (size_t)blockIdx.x * 128 * K;            \
  f32x4 acc[4][4];                                                             \
  _Pragma("unroll") for (int i = 0; i < 4; ++i)                                \
  _Pragma("unroll") for (int j = 0; j < 4; ++j)                                \
      acc[i][j] = (f32x4){0.f, 0.f, 0.f, 0.f};                                 \
  gemm_core(Ablk, Bblk, K, As, Bs, acc);                                       \
  const int lane = threadIdx.x & 63;                                           \
  const int wv = threadIdx.x >> 6;                                             \
  const int wm = wv & 1, wn = wv >> 1;                                         \
  const int t = lane & 15, quad = lane >> 4;                                   \
  const int gm_base = blockIdx.y * 128 + wm * 64;                              \
  const int gn_base = blockIdx.x * 128 + wn * 64;

// GEMM1: three projections src @ thetaT^T.  z=0 train(+trainT), z=1 label, z=2 test
__global__ __launch_bounds__(256) void gemm_proj(
    const unsigned short* __restrict__ src_bf,
    const unsigned short* __restrict__ thkT,
    const unsigned short* __restrict__ thvT,
    const unsigned short* __restrict__ thqT,
    unsigned short* __restrict__ train,
    unsigned short* __restrict__ trainT,
    unsigned short* __restrict__ label,
    unsigned short* __restrict__ testv) {
  const int z = blockIdx.z;
  const unsigned short* Bmat = (z == 0) ? thkT : (z == 1) ? thvT : thqT;
  GEMM_PROLOGUE(src_bf, Bmat, D_DIM)
  unsigned short* outp = (z == 0) ? train : (z == 1) ? label : testv;
#pragma unroll
  for (int i = 0; i < 4; ++i) {
#pragma unroll
    for (int j = 0; j < 4; ++j) {
      const int gm0 = gm_base + i * 16 + quad * 4;
      const int gn  = gn_base + j * 16 + t;
#pragma unroll
      for (int r = 0; r < 4; ++r)
        outp[(size_t)(gm0 + r) * D_DIM + gn] = f2bf(acc[i][j][r]);
      if (z == 0) {
        ushort4 pk = make_ushort4(f2bf(acc[i][j][0]), f2bf(acc[i][j][1]),
                                  f2bf(acc[i][j][2]), f2bf(acc[i][j][3]));
        *(ushort4*)(trainT + (size_t)gn * B_TOK + gm0) = pk;
      }
    }
  }
}

// GEMM2: err = train@W^T + b + train - label, stored transposed errT[D,B]
__global__ __launch_bounds__(256) void gemm_err(
    const unsigned short* __restrict__ train,
    const unsigned short* __restrict__ Wbf,
    const float* __restrict__ bvec,
    const unsigned short* __restrict__ label,
    unsigned short* __restrict__ errT) {
  GEMM_PROLOGUE(train, Wbf, D_DIM)
#pragma unroll
  for (int i = 0; i < 4; ++i) {
#pragma unroll
    for (int j = 0; j < 4; ++j) {
      const int gm0 = gm_base + i * 16 + quad * 4;
      const int gn  = gn_base + j * 16 + t;
      const float bias = bvec[gn];
      float e[4];
#pragma unroll
      for (int r = 0; r < 4; ++r) {
        const size_t idx = (size_t)(gm0 + r) * D_DIM + gn;
        e[r] = acc[i][j][r] + bias + bf2f(train[idx]) - bf2f(label[idx]);
      }
      ushort4 pk = make_ushort4(f2bf(e[0]), f2bf(e[1]), f2bf(e[2]), f2bf(e[3]));
      *(ushort4*)(errT + (size_t)gn * B_TOK + gm0) = pk;
    }
  }
}

// GEMM3: gW = coef * errT @ trainT^T ; W_new = W - lr_w*gW  (bf16 out)
__global__ __launch_bounds__(256) void gemm_gw(
    const unsigned short* __restrict__ errT,
    const unsigned short* __restrict__ trainT,
    const float* __restrict__ W,
    const float* __restrict__ lr_w,
    unsigned short* __restrict__ Wnew) {
  GEMM_PROLOGUE(errT, trainT, B_TOK)
#pragma unroll
  for (int i = 0; i < 4; ++i) {
#pragma unroll
    for (int j = 0; j < 4; ++j) {
      const int gm0 = gm_base + i * 16 + quad * 4;
      const int gn  = gn_base + j * 16 + t;
#pragma unroll
      for (int r = 0; r < 4; ++r) {
        const size_t idx = (size_t)(gm0 + r) * D_DIM + gn;
        const float gw = COEF * acc[i][j][r];
        Wnew[idx] = f2bf(W[idx] - lr_w[idx] * gw);
      }
    }
  }
}

// GEMM4: z = test @ Wnew^T + b_new + test  (f32 out)
__global__ __launch_bounds__(256) void gemm_out(
    const unsigned short* __restrict__ testv,
    const unsigned short* __restrict__ Wnew,
    const float* __restrict__ b_new,
    float* __restrict__ out) {
  GEMM_PROLOGUE(testv, Wnew, D_DIM)
#pragma unroll
  for (int i = 0; i < 4; ++i) {
#pragma unroll
    for (int j = 0; j < 4; ++j) {
      const int gm0 = gm_base + i * 16 + quad * 4;
      const int gn  = gn_base + j * 16 + t;
      const float bias = b_new[gn];
#pragma unroll
      for (int r = 0; r < 4; ++r) {
        const size_t idx = (size_t)(gm0 + r) * D_DIM + gn;
        out[idx] = acc[i][j][r] + bias + bf2f(testv[idx]);
      }
    }
  }
}

// f32 -> bf16 convert, 4 elems/thread
__global__ __launch_bounds__(256) void cvt_bf16(const float* __restrict__ in,
                                                unsigned short* __restrict__ out,
                                                int n4) {
  const int i = blockIdx.x * 256 + threadIdx.x;
  if (i < n4) {
    const float4 v = ((const float4*)in)[i];
    ((ushort4*)out)[i] = make_ushort4(f2bf(v.x), f2bf(v.y), f2bf(v.z), f2bf(v.w));
  }
}

// transpose + convert the three [D,D] thetas: out[n*D+k] = in[k*D+n]
__global__ __launch_bounds__(256) void tcvt(
    const float* __restrict__ a0, const float* __restrict__ a1, const float* __restrict__ a2,
    unsigned short* __restrict__ o0, unsigned short* __restrict__ o1, unsigned short* __restrict__ o2) {
  __shared__ float tile[32][33];
  const float* in = (blockIdx.z == 0) ? a0 : (blockIdx.z == 1) ? a1 : a2;
  unsigned short* out = (blockIdx.z == 0) ? o0 : (blockIdx.z == 1) ? o1 : o2;
  const int bx = blockIdx.x * 32, by = blockIdx.y * 32;
  const int tx = threadIdx.x, ty = threadIdx.y;
#pragma unroll
  for (int l = 0; l < 4; ++l) {
    const int r = ty + l * 8;
    tile[r][tx] = in[(size_t)(by + r) * D_DIM + bx + tx];
  }
  __syncthreads();
#pragma unroll
  for (int l = 0; l < 4; ++l) {
    const int r = ty + l * 8;
    out[(size_t)(bx + r) * D_DIM + by + tx] = f2bf(tile[tx][r]);
  }
}

// gb[i] = sum_b errT[i,b]; b_new[i] = b[i] - lr_b[i]*coef*gb[i]. 1 wave/row.
__global__ __launch_bounds__(256) void colsum_bnew(
    const unsigned short* __restrict__ errT,
    const float* __restrict__ bvec,
    const float* __restrict__ lr_b,
    float* __restrict__ b_new) {
  const int wv = threadIdx.x >> 6, lane = threadIdx.x & 63;
  const int row = blockIdx.x * 4 + wv;
  const ushort4* p = (const ushort4*)(errT + (size_t)row * B_TOK);
  float s = 0.f;
#pragma unroll
  for (int j = 0; j < 16; ++j) {
    const ushort4 u = p[j * 64 + lane];
    s += bf2f(u.x) + bf2f(u.y) + bf2f(u.z) + bf2f(u.w);
  }
#pragma unroll
  for (int off = 32; off; off >>= 1) s += __shfl_down(s, off);
  if (lane == 0) b_new[row] = bvec[row] - lr_b[row] * (COEF * s);
}

extern "C" void kernel_launch(void* const* d_in, const int* in_sizes, int n_in,
                              void* d_out, int out_size, void* d_ws, size_t ws_size,
                              hipStream_t stream) {
  const float* src = (const float*)d_in[0];
  const float* thk = (const float*)d_in[1];
  const float* thq = (const float*)d_in[2];
  const float* thv = (const float*)d_in[3];
  const float* W   = (const float*)d_in[4];
  const float* bv  = (const float*)d_in[5];
  const float* lrw = (const float*)d_in[6];
  const float* lrb = (const float*)d_in[7];
  float* out = (float*)d_out;

  char* ws = (char*)d_ws;
  const size_t MB = 1024 * 1024;
  unsigned short* src_bf = (unsigned short*)(ws + 0);        // 16 MB
  unsigned short* thkT   = (unsigned short*)(ws + 16 * MB);  //  8 MB
  unsigned short* thvT   = (unsigned short*)(ws + 24 * MB);  //  8 MB
  unsigned short* thqT   = (unsigned short*)(ws + 32 * MB);  //  8 MB
  unsigned short* Wbf    = (unsigned short*)(ws + 40 * MB);  //  8 MB (Wnew later)
  unsigned short* train  = (unsigned short*)(ws + 48 * MB);  // 16 MB
  unsigned short* trainT = (unsigned short*)(ws + 64 * MB);  // 16 MB
  unsigned short* label  = (unsigned short*)(ws + 80 * MB);  // 16 MB
  unsigned short* testv  = (unsigned short*)(ws + 96 * MB);  // 16 MB
  unsigned short* errT   = (unsigned short*)(ws + 112 * MB); // 16 MB
  float*          b_new  = (float*)(ws + 128 * MB);          //  8 KB

  cvt_bf16<<<8192, 256, 0, stream>>>(src, src_bf, 2097152);
  cvt_bf16<<<4096, 256, 0, stream>>>(W, Wbf, 1048576);
  tcvt<<<dim3(64, 64, 3), dim3(32, 8), 0, stream>>>(thk, thq, thv, thkT, thqT, thvT);

  gemm_proj<<<dim3(16, 32, 3), 256, 0, stream>>>(src_bf, thkT, thvT, thqT,
                                                 train, trainT, label, testv);
  gemm_err<<<dim3(16, 32), 256, 0, stream>>>(train, Wbf, bv, label, errT);
  colsum_bnew<<<512, 256, 0, stream>>>(errT, bv, lrb, b_new);
  gemm_gw<<<dim3(16, 16), 256, 0, stream>>>(errT, trainT, W, lrw, Wbf);  // Wnew -> Wbf
  gemm_out<<<dim3(16, 32), 256, 0, stream>>>(testv, Wbf, b_new, out);
}

// Round 2
// 450.202 us; speedup vs baseline: 1.0520x; 1.0520x over previous
//
#include <hip/hip_runtime.h>
#include <hip/hip_bf16.h>
#include <stdint.h>

#define D_DIM 2048
#define B_TOK 4096
#define COEF (2.0f / 8388608.0f)   // 2/(B*D)

typedef __bf16 bf16x8 __attribute__((ext_vector_type(8)));
typedef float  f32x4  __attribute__((ext_vector_type(4)));

__device__ __forceinline__ unsigned short f2bf(float f) {
  return __builtin_bit_cast(unsigned short, (__bf16)f);
}
__device__ __forceinline__ float bf2f(unsigned short u) {
  return (float)__builtin_bit_cast(__bf16, u);
}

// async global->LDS, 16B per lane; LDS dest = wave-uniform base + lane*16
__device__ __forceinline__ void async16(const void* g, void* l) {
  __builtin_amdgcn_global_load_lds(
      (__attribute__((address_space(1))) void*)(g),
      (__attribute__((address_space(3))) void*)(l),
      16, 0, 0);
}

// ---------------------------------------------------------------------------
// Core bt-GEMM: C[128x128] tile, A row-major (ld), B row-major (ld), loops KC.
// BK=64, 4 waves (2x2), each wave 64x64 via 4x4 mfma_f32_16x16x32_bf16.
// LDS chunk swizzle: LDS(row, c) holds global chunk (row, c ^ (row&7)) so
// quad fragment reads are 2-way bank aliased (free) instead of 16-way.
// ---------------------------------------------------------------------------
__device__ __forceinline__ void gemm_core(const unsigned short* __restrict__ Ablk,
                                          const unsigned short* __restrict__ Bblk,
                                          const int ld, const int KC,
                                          unsigned short* As, unsigned short* Bs,
                                          f32x4 acc[4][4]) {
  const int tid  = threadIdx.x;
  const int lane = tid & 63;
  const int wv   = tid >> 6;
  const int wm   = wv & 1, wn = wv >> 1;
  const int t    = lane & 15;
  const int quad = lane >> 4;
  const int lrow = lane >> 3;      // 0..7 within an 8-row staging segment
  const int kq   = lane & 7;       // 16B chunk within a 64-col row
  const int kqs  = kq ^ lrow;      // swizzled source chunk (row&7 == lrow)

  const int nk = KC >> 6;
  for (int kt = 0; kt < nk; ++kt) {
    const int k0 = kt << 6;
#pragma unroll
    for (int l = 0; l < 4; ++l) {
      const int seg = wv * 4 + l;           // 16 segments of 8 rows
      const int r   = seg * 8 + lrow;
      const size_t goff = (size_t)r * ld + k0 + kqs * 8;
      async16(Ablk + goff, As + seg * 512);
      async16(Bblk + goff, Bs + seg * 512);
    }
    __syncthreads();                         // drains vmcnt, staging visible
#pragma unroll
    for (int s = 0; s < 2; ++s) {            // two K=32 MFMA steps per BK=64
      bf16x8 af[4], bfr[4];
#pragma unroll
      for (int i = 0; i < 4; ++i) {
        const int rm = wm * 64 + i * 16 + t;
        af[i]  = *(const bf16x8*)(As + rm * 64 + (((s << 2) + quad) ^ (rm & 7)) * 8);
        const int rn = wn * 64 + i * 16 + t;
        bfr[i] = *(const bf16x8*)(Bs + rn * 64 + (((s << 2) + quad) ^ (rn & 7)) * 8);
      }
#pragma unroll
      for (int i = 0; i < 4; ++i)
#pragma unroll
        for (int j = 0; j < 4; ++j)
          acc[i][j] = __builtin_amdgcn_mfma_f32_16x16x32_bf16(af[i], bfr[j], acc[i][j], 0, 0, 0);
    }
    __syncthreads();                         // all reads done before next stage
  }
}

#define GEMM_PROLOGUE(AP, BP, LDv, KCv)                                        \
  __shared__ __align__(16) unsigned short As[128 * 64];                        \
  __shared__ __align__(16) unsigned short Bs[128 * 64];                        \
  const int LD = (LDv);                                                        \
  const unsigned short* Ablk = (AP) + (size_t)blockIdx.y * 128 * LD;           \
  const unsigned short* Bblk = (BP) + (size_t)blockIdx.x * 128 * LD;           \
  f32x4 acc[4][4];                                                             \
  _Pragma("unroll") for (int i = 0; i < 4; ++i)                                \
  _Pragma("unroll") for (int j = 0; j < 4; ++j)                                \
      acc[i][j] = (f32x4){0.f, 0.f, 0.f, 0.f};                                 \
  gemm_core(Ablk, Bblk, LD, (KCv), As, Bs, acc);                               \
  const int lane = threadIdx.x & 63;                                           \
  const int wv = threadIdx.x >> 6;                                             \
  const int wm = wv & 1, wn = wv >> 1;                                         \
  const int t = lane & 15, quad = lane >> 4;                                   \
  const int gm_base = blockIdx.y * 128 + wm * 64;                              \
  const int gn_base = blockIdx.x * 128 + wn * 64;

// GEMM1: projections. z=0: train=src@thk^T (+trainT), z=1: tgt2=src@thd^T, z=2: test
__global__ __launch_bounds__(256) void gemm_proj(
    const unsigned short* __restrict__ src_bf,
    const unsigned short* __restrict__ thkT,
    const unsigned short* __restrict__ thdT,
    const unsigned short* __restrict__ thqT,
    unsigned short* __restrict__ train,
    unsigned short* __restrict__ trainT,
    unsigned short* __restrict__ tgt2,
    unsigned short* __restrict__ testv) {
  const int z = blockIdx.z;
  const unsigned short* Bmat = (z == 0) ? thkT : (z == 1) ? thdT : thqT;
  GEMM_PROLOGUE(src_bf, Bmat, D_DIM, D_DIM)
  unsigned short* outp = (z == 0) ? train : (z == 1) ? tgt2 : testv;
#pragma unroll
  for (int i = 0; i < 4; ++i) {
#pragma unroll
    for (int j = 0; j < 4; ++j) {
      const int gm0 = gm_base + i * 16 + quad * 4;
      const int gn  = gn_base + j * 16 + t;
#pragma unroll
      for (int r = 0; r < 4; ++r)
        outp[(size_t)(gm0 + r) * D_DIM + gn] = f2bf(acc[i][j][r]);
      if (z == 0) {
        ushort4 pk = make_ushort4(f2bf(acc[i][j][0]), f2bf(acc[i][j][1]),
                                  f2bf(acc[i][j][2]), f2bf(acc[i][j][3]));
        *(ushort4*)(trainT + (size_t)gn * B_TOK + gm0) = pk;
      }
    }
  }
}

// GEMM2: err = train@W^T + b - tgt2, stored transposed errT[D,B].
// Also accumulates gb[gn] = sum_rows(err) via cross-quad shuffle + atomicAdd.
__global__ __launch_bounds__(256) void gemm_err(
    const unsigned short* __restrict__ train,
    const unsigned short* __restrict__ Wbf,
    const float* __restrict__ bvec,
    const unsigned short* __restrict__ tgt2,
    unsigned short* __restrict__ errT,
    float* __restrict__ gb) {
  GEMM_PROLOGUE(train, Wbf, D_DIM, D_DIM)
#pragma unroll
  for (int j = 0; j < 4; ++j) {
    const int gn = gn_base + j * 16 + t;
    const float bias = bvec[gn];
    float cs = 0.f;
#pragma unroll
    for (int i = 0; i < 4; ++i) {
      const int gm0 = gm_base + i * 16 + quad * 4;
      float e[4];
#pragma unroll
      for (int r = 0; r < 4; ++r) {
        const size_t idx = (size_t)(gm0 + r) * D_DIM + gn;
        e[r] = acc[i][j][r] + bias - bf2f(tgt2[idx]);
      }
      ushort4 pk = make_ushort4(f2bf(e[0]), f2bf(e[1]), f2bf(e[2]), f2bf(e[3]));
      *(ushort4*)(errT + (size_t)gn * B_TOK + gm0) = pk;
      cs += e[0] + e[1] + e[2] + e[3];
    }
    cs += __shfl_xor(cs, 16);
    cs += __shfl_xor(cs, 32);
    if (quad == 0) atomicAdd(&gb[gn], cs);
  }
}

// GEMM3 (split-K=2): P_z = errT[:, z*2048:+2048] @ trainT[:, same]^T, f32 partials
__global__ __launch_bounds__(256) void gemm_gw(
    const unsigned short* __restrict__ errT,
    const unsigned short* __restrict__ trainT,
    float* __restrict__ P0, float* __restrict__ P1) {
  const int z = blockIdx.z;
  const unsigned short* Abase = errT + z * 2048;
  const unsigned short* Bbase = trainT + z * 2048;
  GEMM_PROLOGUE(Abase, Bbase, B_TOK, 2048)
  float* P = (z == 0) ? P0 : P1;
#pragma unroll
  for (int i = 0; i < 4; ++i) {
#pragma unroll
    for (int j = 0; j < 4; ++j) {
      const int gm0 = gm_base + i * 16 + quad * 4;
      const int gn  = gn_base + j * 16 + t;
#pragma unroll
      for (int r = 0; r < 4; ++r)
        P[(size_t)(gm0 + r) * D_DIM + gn] = acc[i][j][r];
    }
  }
}

// Reduce partials + SGD update: Wnew = bf16(W - lr_w * COEF * (P0+P1))
__global__ __launch_bounds__(256) void wnew_reduce(
    const float* __restrict__ P0, const float* __restrict__ P1,
    const float* __restrict__ W, const float* __restrict__ lr_w,
    unsigned short* __restrict__ Wnew) {
  const int i = blockIdx.x * 256 + threadIdx.x;   // 1M float4 groups
  const float4 p0 = ((const float4*)P0)[i];
  const float4 p1 = ((const float4*)P1)[i];
  const float4 w  = ((const float4*)W)[i];
  const float4 l  = ((const float4*)lr_w)[i];
  ((ushort4*)Wnew)[i] = make_ushort4(
      f2bf(w.x - l.x * (COEF * (p0.x + p1.x))),
      f2bf(w.y - l.y * (COEF * (p0.y + p1.y))),
      f2bf(w.z - l.z * (COEF * (p0.z + p1.z))),
      f2bf(w.w - l.w * (COEF * (p0.w + p1.w))));
}

// GEMM4: z = test @ Wnew^T + b_new + test, b_new computed inline from gb
__global__ __launch_bounds__(256) void gemm_out(
    const unsigned short* __restrict__ testv,
    const unsigned short* __restrict__ Wnew,
    const float* __restrict__ bvec,
    const float* __restrict__ lr_b,
    const float* __restrict__ gb,
    float* __restrict__ out) {
  GEMM_PROLOGUE(testv, Wnew, D_DIM, D_DIM)
#pragma unroll
  for (int j = 0; j < 4; ++j) {
    const int gn = gn_base + j * 16 + t;
    const float bias = bvec[gn] - lr_b[gn] * (COEF * gb[gn]);
#pragma unroll
    for (int i = 0; i < 4; ++i) {
      const int gm0 = gm_base + i * 16 + quad * 4;
#pragma unroll
      for (int r = 0; r < 4; ++r) {
        const size_t idx = (size_t)(gm0 + r) * D_DIM + gn;
        out[idx] = acc[i][j][r] + bias + bf2f(testv[idx]);
      }
    }
  }
}

// f32 -> bf16 convert for src (first 2M groups) then W (next 1M groups);
// first 512 threads also zero gb.
__global__ __launch_bounds__(256) void cvt_all(const float* __restrict__ src,
                                               const float* __restrict__ W,
                                               unsigned short* __restrict__ src_bf,
                                               unsigned short* __restrict__ Wbf,
                                               float* __restrict__ gb) {
  const int i = blockIdx.x * 256 + threadIdx.x;   // 0 .. 3145727
  if (i < 512) ((float4*)gb)[i] = (float4){0.f, 0.f, 0.f, 0.f};
  if (i < 2097152) {
    const float4 v = ((const float4*)src)[i];
    ((ushort4*)src_bf)[i] = make_ushort4(f2bf(v.x), f2bf(v.y), f2bf(v.z), f2bf(v.w));
  } else {
    const int j = i - 2097152;
    const float4 v = ((const float4*)W)[j];
    ((ushort4*)Wbf)[j] = make_ushort4(f2bf(v.x), f2bf(v.y), f2bf(v.z), f2bf(v.w));
  }
}

// transpose+convert: z=0: thk^T, z=1: thq^T, z=2: (thv-thk)^T
__global__ __launch_bounds__(256) void tcvt(
    const float* __restrict__ thk, const float* __restrict__ thq,
    const float* __restrict__ thv,
    unsigned short* __restrict__ o0, unsigned short* __restrict__ o1,
    unsigned short* __restrict__ o2) {
  __shared__ float tile[32][33];
  const int z = blockIdx.z;
  unsigned short* out = (z == 0) ? o0 : (z == 1) ? o1 : o2;
  const int bx = blockIdx.x * 32, by = blockIdx.y * 32;
  const int tx = threadIdx.x, ty = threadIdx.y;
#pragma unroll
  for (int l = 0; l < 4; ++l) {
    const int r = ty + l * 8;
    const size_t idx = (size_t)(by + r) * D_DIM + bx + tx;
    tile[r][tx] = (z == 0) ? thk[idx] : (z == 1) ? thq[idx] : (thv[idx] - thk[idx]);
  }
  __syncthreads();
#pragma unroll
  for (int l = 0; l < 4; ++l) {
    const int r = ty + l * 8;
    out[(size_t)(bx + r) * D_DIM + by + tx] = f2bf(tile[tx][r]);
  }
}

extern "C" void kernel_launch(void* const* d_in, const int* in_sizes, int n_in,
                              void* d_out, int out_size, void* d_ws, size_t ws_size,
                              hipStream_t stream) {
  const float* src = (const float*)d_in[0];
  const float* thk = (const float*)d_in[1];
  const float* thq = (const float*)d_in[2];
  const float* thv = (const float*)d_in[3];
  const float* W   = (const float*)d_in[4];
  const float* bv  = (const float*)d_in[5];
  const float* lrw = (const float*)d_in[6];
  const float* lrb = (const float*)d_in[7];
  float* out = (float*)d_out;

  char* ws = (char*)d_ws;
  const size_t MB = 1024 * 1024;
  unsigned short* src_bf = (unsigned short*)(ws + 0);        // 16 MB (dead after proj)
  unsigned short* thkT   = (unsigned short*)(ws + 16 * MB);  //  8 MB
  unsigned short* thqT   = (unsigned short*)(ws + 24 * MB);  //  8 MB
  unsigned short* thdT   = (unsigned short*)(ws + 32 * MB);  //  8 MB
  unsigned short* Wbf    = (unsigned short*)(ws + 40 * MB);  //  8 MB (Wnew later)
  unsigned short* train  = (unsigned short*)(ws + 48 * MB);  // 16 MB (dead after err)
  unsigned short* trainT = (unsigned short*)(ws + 64 * MB);  // 16 MB
  unsigned short* tgt2   = (unsigned short*)(ws + 80 * MB);  // 16 MB
  unsigned short* testv  = (unsigned short*)(ws + 96 * MB);  // 16 MB
  unsigned short* errT   = (unsigned short*)(ws + 112 * MB); // 16 MB
  float*          gb     = (float*)(ws + 128 * MB);          //  8 KB
  float*          P0     = (float*)(ws + 0);                 // 16 MB (reuse src_bf)
  float*          P1     = (float*)(ws + 48 * MB);           // 16 MB (reuse train)

  cvt_all<<<12288, 256, 0, stream>>>(src, W, src_bf, Wbf, gb);
  tcvt<<<dim3(64, 64, 3), dim3(32, 8), 0, stream>>>(thk, thq, thv, thkT, thqT, thdT);

  gemm_proj<<<dim3(16, 32, 3), 256, 0, stream>>>(src_bf, thkT, thdT, thqT,
                                                 train, trainT, tgt2, testv);
  gemm_err<<<dim3(16, 32), 256, 0, stream>>>(train, Wbf, bv, tgt2, errT, gb);
  gemm_gw<<<dim3(16, 16, 2), 256, 0, stream>>>(errT, trainT, P0, P1);
  wnew_reduce<<<4096, 256, 0, stream>>>(P0, P1, W, lrw, Wbf);  // Wnew -> Wbf
  gemm_out<<<dim3(16, 32), 256, 0, stream>>>(testv, Wbf, bv, lrb, gb, out);
}

// Round 4
// 438.924 us; speedup vs baseline: 1.0790x; 1.0257x over previous
//
#include <hip/hip_runtime.h>
#include <hip/hip_bf16.h>
#include <stdint.h>

#define D_DIM 2048
#define B_TOK 4096
#define COEF (2.0f / 8388608.0f)   // 2/(B*D)

typedef __bf16 bf16x8 __attribute__((ext_vector_type(8)));
typedef float  f32x4  __attribute__((ext_vector_type(4)));
typedef unsigned short u16x8 __attribute__((ext_vector_type(8)));

__device__ __forceinline__ unsigned short f2bf(float f) {
  return __builtin_bit_cast(unsigned short, (__bf16)f);
}
__device__ __forceinline__ float bf2f(unsigned short u) {
  return (float)__builtin_bit_cast(__bf16, u);
}

// async global->LDS, 16B per lane; LDS dest = wave-uniform base + lane*16
__device__ __forceinline__ void async16(const void* g, void* l) {
  __builtin_amdgcn_global_load_lds(
      (__attribute__((address_space(1))) void*)(g),
      (__attribute__((address_space(3))) void*)(l),
      16, 0, 0);
}

// ---------------------------------------------------------------------------
// Core bt-GEMM: C[128x128] tile, A row-major (lda), B row-major (ldb), K=KC.
// BK=64, 4 waves (2x2), each wave 64x64 via 4x4 mfma_f32_16x16x32_bf16.
// LDS chunk swizzle: LDS(row, c) holds global chunk (row, c ^ (row&7)) so
// quad fragment reads are 2-way bank aliased (free) instead of 16-way.
// ---------------------------------------------------------------------------
__device__ __forceinline__ void gemm_core(const unsigned short* __restrict__ Ablk,
                                          const unsigned short* __restrict__ Bblk,
                                          const int lda, const int ldb, const int KC,
                                          unsigned short* As, unsigned short* Bs,
                                          f32x4 acc[4][4]) {
  const int tid  = threadIdx.x;
  const int lane = tid & 63;
  const int wv   = tid >> 6;
  const int wm   = wv & 1, wn = wv >> 1;
  const int t    = lane & 15;
  const int quad = lane >> 4;
  const int lrow = lane >> 3;      // 0..7 within an 8-row staging segment
  const int kq   = lane & 7;       // 16B chunk within a 64-col row
  const int kqs  = kq ^ lrow;      // swizzled source chunk (row&7 == lrow)

  const int nk = KC >> 6;
  for (int kt = 0; kt < nk; ++kt) {
    const int k0 = kt << 6;
#pragma unroll
    for (int l = 0; l < 4; ++l) {
      const int seg = wv * 4 + l;           // 16 segments of 8 rows
      const int r   = seg * 8 + lrow;
      async16(Ablk + (size_t)r * lda + k0 + kqs * 8, As + seg * 512);
      async16(Bblk + (size_t)r * ldb + k0 + kqs * 8, Bs + seg * 512);
    }
    __syncthreads();                         // drains vmcnt, staging visible
#pragma unroll
    for (int s = 0; s < 2; ++s) {            // two K=32 MFMA steps per BK=64
      bf16x8 af[4], bfr[4];
#pragma unroll
      for (int i = 0; i < 4; ++i) {
        const int rm = wm * 64 + i * 16 + t;
        af[i]  = *(const bf16x8*)(As + rm * 64 + (((s << 2) + quad) ^ (rm & 7)) * 8);
        const int rn = wn * 64 + i * 16 + t;
        bfr[i] = *(const bf16x8*)(Bs + rn * 64 + (((s << 2) + quad) ^ (rn & 7)) * 8);
      }
#pragma unroll
      for (int i = 0; i < 4; ++i)
#pragma unroll
        for (int j = 0; j < 4; ++j)
          acc[i][j] = __builtin_amdgcn_mfma_f32_16x16x32_bf16(af[i], bfr[j], acc[i][j], 0, 0, 0);
    }
    __syncthreads();                         // all reads done before next stage
  }
}

#define GEMM_PROLOGUE(AP, BP, LDAv, LDBv, KCv)                                 \
  __shared__ __align__(16) unsigned short As[128 * 64];                        \
  __shared__ __align__(16) unsigned short Bs[128 * 64];                        \
  const unsigned short* Ablk = (AP) + (size_t)blockIdx.y * 128 * (LDAv);       \
  const unsigned short* Bblk = (BP) + (size_t)blockIdx.x * 128 * (LDBv);       \
  f32x4 acc[4][4];                                                             \
  _Pragma("unroll") for (int i = 0; i < 4; ++i)                                \
  _Pragma("unroll") for (int j = 0; j < 4; ++j)                                \
      acc[i][j] = (f32x4){0.f, 0.f, 0.f, 0.f};                                 \
  gemm_core(Ablk, Bblk, (LDAv), (LDBv), (KCv), As, Bs, acc);                   \
  const int lane = threadIdx.x & 63;                                           \
  const int wv = threadIdx.x >> 6;                                             \
  const int wm = wv & 1, wn = wv >> 1;                                         \
  const int t = lane & 15, quad = lane >> 4;                                   \
  const int gm_base = blockIdx.y * 128 + wm * 64;                              \
  const int gn_base = blockIdx.x * 128 + wn * 64;

// GEMM1: projections, A = src_cat right half (lda 4096).
// z=0: train=src@thk^T -> src_cat left half (ld 4096) + trainT (LDS-transposed)
// z=1: test=src@thq^T -> testv (ld 2048)
__global__ __launch_bounds__(256) void gemm_proj(
    const unsigned short* __restrict__ srcA,   // src_cat + 2048
    const unsigned short* __restrict__ thkT,
    const unsigned short* __restrict__ thqT,
    unsigned short* __restrict__ src_cat,      // train goes to left half
    unsigned short* __restrict__ trainT,
    unsigned short* __restrict__ testv) {
  const int z = blockIdx.z;
  const unsigned short* Bmat = (z == 0) ? thkT : thqT;
  GEMM_PROLOGUE(srcA, Bmat, 4096, 2048, D_DIM)
  if (z == 0) {
    unsigned short* scr = ((wv >> 1) ? Bs : As) + (wv & 1) * 2304;  // 32 rows x 72
#pragma unroll
    for (int p = 0; p < 2; ++p) {
#pragma unroll
      for (int jl = 0; jl < 2; ++jl) {
        const int j = p * 2 + jl;
        const int gn = gn_base + j * 16 + t;
#pragma unroll
        for (int i = 0; i < 4; ++i) {
          const int gm0 = gm_base + i * 16 + quad * 4;
          ushort4 pk = make_ushort4(f2bf(acc[i][j][0]), f2bf(acc[i][j][1]),
                                    f2bf(acc[i][j][2]), f2bf(acc[i][j][3]));
          src_cat[(size_t)(gm0 + 0) * 4096 + gn] = pk.x;
          src_cat[(size_t)(gm0 + 1) * 4096 + gn] = pk.y;
          src_cat[(size_t)(gm0 + 2) * 4096 + gn] = pk.z;
          src_cat[(size_t)(gm0 + 3) * 4096 + gn] = pk.w;
          *(ushort4*)(scr + (jl * 16 + t) * 72 + i * 16 + quad * 4) = pk;
        }
      }
      __syncthreads();
      const int row = lane >> 3, chunk = lane & 7;
#pragma unroll
      for (int q = 0; q < 4; ++q) {
        const int rr = q * 8 + row;
        u16x8 v = *(const u16x8*)(scr + rr * 72 + chunk * 8);
        *(u16x8*)(trainT + (size_t)(gn_base + p * 32 + rr) * B_TOK + gm_base + chunk * 8) = v;
      }
      __syncthreads();
    }
  } else {
#pragma unroll
    for (int i = 0; i < 4; ++i) {
#pragma unroll
      for (int j = 0; j < 4; ++j) {
        const int gm0 = gm_base + i * 16 + quad * 4;
        const int gn  = gn_base + j * 16 + t;
#pragma unroll
        for (int r = 0; r < 4; ++r)
          testv[(size_t)(gm0 + r) * D_DIM + gn] = f2bf(acc[i][j][r]);
      }
    }
  }
}

// GEMM2 (K=4096): err = [train|src] @ [W | (thk-thv)^T]^T + b
// = train@W^T + b - (label-train).  Stored transposed errT[D,B_TOK] via LDS.
// Also accumulates gb[gn] via cross-quad shuffle + atomicAdd.
__global__ __launch_bounds__(256) void gemm_err(
    const unsigned short* __restrict__ src_cat,
    const unsigned short* __restrict__ Wcat,
    const float* __restrict__ bvec,
    unsigned short* __restrict__ errT,
    float* __restrict__ gb) {
  GEMM_PROLOGUE(src_cat, Wcat, 4096, 4096, 4096)
  unsigned short* scr = ((wv >> 1) ? Bs : As) + (wv & 1) * 2304;
#pragma unroll
  for (int p = 0; p < 2; ++p) {
#pragma unroll
    for (int jl = 0; jl < 2; ++jl) {
      const int j = p * 2 + jl;
      const int gn = gn_base + j * 16 + t;
      const float bias = bvec[gn];
      float cs = 0.f;
#pragma unroll
      for (int i = 0; i < 4; ++i) {
        float e0 = acc[i][j][0] + bias, e1 = acc[i][j][1] + bias;
        float e2 = acc[i][j][2] + bias, e3 = acc[i][j][3] + bias;
        ushort4 pk = make_ushort4(f2bf(e0), f2bf(e1), f2bf(e2), f2bf(e3));
        *(ushort4*)(scr + (jl * 16 + t) * 72 + i * 16 + quad * 4) = pk;
        cs += e0 + e1 + e2 + e3;
      }
      cs += __shfl_xor(cs, 16);
      cs += __shfl_xor(cs, 32);
      if (quad == 0) atomicAdd(&gb[gn], cs);
    }
    __syncthreads();
    const int row = lane >> 3, chunk = lane & 7;
#pragma unroll
    for (int q = 0; q < 4; ++q) {
      const int rr = q * 8 + row;
      u16x8 v = *(const u16x8*)(scr + rr * 72 + chunk * 8);
      *(u16x8*)(errT + (size_t)(gn_base + p * 32 + rr) * B_TOK + gm_base + chunk * 8) = v;
    }
    __syncthreads();
  }
}

// GEMM3 (split-K=2): P_z = errT[:, z*2048:+2048] @ trainT[:, same]^T, f32 partials
__global__ __launch_bounds__(256) void gemm_gw(
    const unsigned short* __restrict__ errT,
    const unsigned short* __restrict__ trainT,
    float* __restrict__ P0, float* __restrict__ P1) {
  const int z = blockIdx.z;
  const unsigned short* Abase = errT + z * 2048;
  const unsigned short* Bbase = trainT + z * 2048;
  GEMM_PROLOGUE(Abase, Bbase, B_TOK, B_TOK, 2048)
  float* P = (z == 0) ? P0 : P1;
#pragma unroll
  for (int i = 0; i < 4; ++i) {
#pragma unroll
    for (int j = 0; j < 4; ++j) {
      const int gm0 = gm_base + i * 16 + quad * 4;
      const int gn  = gn_base + j * 16 + t;
#pragma unroll
      for (int r = 0; r < 4; ++r)
        P[(size_t)(gm0 + r) * D_DIM + gn] = acc[i][j][r];
    }
  }
}

// Reduce partials + SGD update: Wnew = bf16(W - lr_w * COEF * (P0+P1))
__global__ __launch_bounds__(256) void wnew_reduce(
    const float* __restrict__ P0, const float* __restrict__ P1,
    const float* __restrict__ W, const float* __restrict__ lr_w,
    unsigned short* __restrict__ Wnew) {
  const int i = blockIdx.x * 256 + threadIdx.x;   // 1M float4 groups
  const float4 p0 = ((const float4*)P0)[i];
  const float4 p1 = ((const float4*)P1)[i];
  const float4 w  = ((const float4*)W)[i];
  const float4 l  = ((const float4*)lr_w)[i];
  ((ushort4*)Wnew)[i] = make_ushort4(
      f2bf(w.x - l.x * (COEF * (p0.x + p1.x))),
      f2bf(w.y - l.y * (COEF * (p0.y + p1.y))),
      f2bf(w.z - l.z * (COEF * (p0.z + p1.z))),
      f2bf(w.w - l.w * (COEF * (p0.w + p1.w))));
}

// GEMM4: z = test @ Wnew^T + b_new + test, b_new computed inline from gb
__global__ __launch_bounds__(256) void gemm_out(
    const unsigned short* __restrict__ testv,
    const unsigned short* __restrict__ Wnew,
    const float* __restrict__ bvec,
    const float* __restrict__ lr_b,
    const float* __restrict__ gb,
    float* __restrict__ out) {
  GEMM_PROLOGUE(testv, Wnew, D_DIM, D_DIM, D_DIM)
#pragma unroll
  for (int j = 0; j < 4; ++j) {
    const int gn = gn_base + j * 16 + t;
    const float bias = bvec[gn] - lr_b[gn] * (COEF * gb[gn]);
#pragma unroll
    for (int i = 0; i < 4; ++i) {
      const int gm0 = gm_base + i * 16 + quad * 4;
#pragma unroll
      for (int r = 0; r < 4; ++r) {
        const size_t idx = (size_t)(gm0 + r) * D_DIM + gn;
        out[idx] = acc[i][j][r] + bias + bf2f(testv[idx]);
      }
    }
  }
}

// f32 -> bf16 conversions: src -> src_cat right half (ld 4096),
// W -> Wcat left half (ld 4096). First 512 threads zero gb.
__global__ __launch_bounds__(256) void cvt_all(const float* __restrict__ src,
                                               const float* __restrict__ W,
                                               unsigned short* __restrict__ src_cat,
                                               unsigned short* __restrict__ Wcat,
                                               float* __restrict__ gb) {
  const int i = blockIdx.x * 256 + threadIdx.x;   // 0 .. 3145727
  if (i < 512) ((float4*)gb)[i] = (float4){0.f, 0.f, 0.f, 0.f};
  if (i < 2097152) {
    const int m = i >> 9, c = i & 511;            // 512 float4 per src row
    const float4 v = ((const float4*)src)[i];
    ((ushort4*)src_cat)[(size_t)m * 1024 + 512 + c] =
        make_ushort4(f2bf(v.x), f2bf(v.y), f2bf(v.z), f2bf(v.w));
  } else {
    const int j = i - 2097152;
    const int n = j >> 9, c = j & 511;
    const float4 v = ((const float4*)W)[j];
    ((ushort4*)Wcat)[(size_t)n * 1024 + c] =
        make_ushort4(f2bf(v.x), f2bf(v.y), f2bf(v.z), f2bf(v.w));
  }
}

// transpose+convert: z=0: thk^T -> thkT (ld 2048), z=1: thq^T -> thqT (ld 2048),
// z=2: (thk-thv)^T -> Wcat right half (ld 4096, col offset 2048)
__global__ __launch_bounds__(256) void tcvt(
    const float* __restrict__ thk, const float* __restrict__ thq,
    const float* __restrict__ thv,
    unsigned short* __restrict__ thkT, unsigned short* __restrict__ thqT,
    unsigned short* __restrict__ Wcat) {
  __shared__ float tile[32][33];
  const int z = blockIdx.z;
  const int bx = blockIdx.x * 32, by = blockIdx.y * 32;
  const int tx = threadIdx.x & 31, ty = threadIdx.x >> 5;
#pragma unroll
  for (int l = 0; l < 4; ++l) {
    const int r = ty + l * 8;
    const size_t idx = (size_t)(by + r) * D_DIM + bx + tx;
    tile[r][tx] = (z == 0) ? thk[idx] : (z == 1) ? thq[idx] : (thk[idx] - thv[idx]);
  }
  __syncthreads();
#pragma unroll
  for (int l = 0; l < 4; ++l) {
    const int r = ty + l * 8;
    if (z == 2)
      Wcat[(size_t)(bx + r) * 4096 + 2048 + by + tx] = f2bf(tile[tx][r]);
    else if (z == 0)
      thkT[(size_t)(bx + r) * D_DIM + by + tx] = f2bf(tile[tx][r]);
    else
      thqT[(size_t)(bx + r) * D_DIM + by + tx] = f2bf(tile[tx][r]);
  }
}

extern "C" void kernel_launch(void* const* d_in, const int* in_sizes, int n_in,
                              void* d_out, int out_size, void* d_ws, size_t ws_size,
                              hipStream_t stream) {
  const float* src = (const float*)d_in[0];
  const float* thk = (const float*)d_in[1];
  const float* thq = (const float*)d_in[2];
  const float* thv = (const float*)d_in[3];
  const float* W   = (const float*)d_in[4];
  const float* bv  = (const float*)d_in[5];
  const float* lrw = (const float*)d_in[6];
  const float* lrb = (const float*)d_in[7];
  float* out = (float*)d_out;

  char* ws = (char*)d_ws;
  const size_t MB = 1024 * 1024;
  unsigned short* src_cat = (unsigned short*)(ws + 0);        // 32 MB [4096x4096]
  unsigned short* Wcat    = (unsigned short*)(ws + 32 * MB);  // 16 MB [2048x4096]
  unsigned short* thkT    = (unsigned short*)(ws + 48 * MB);  //  8 MB
  unsigned short* thqT    = (unsigned short*)(ws + 56 * MB);  //  8 MB
  unsigned short* trainT  = (unsigned short*)(ws + 64 * MB);  // 16 MB
  unsigned short* testv   = (unsigned short*)(ws + 80 * MB);  // 16 MB
  unsigned short* errT    = (unsigned short*)(ws + 96 * MB);  // 16 MB
  unsigned short* WnewBf  = (unsigned short*)(ws + 112 * MB); //  8 MB
  float*          gb      = (float*)(ws + 120 * MB);          //  8 KB
  float*          P0      = (float*)(ws + 0);                 // 16 MB (src_cat dead after err)
  float*          P1      = (float*)(ws + 16 * MB);           // 16 MB

  cvt_all<<<12288, 256, 0, stream>>>(src, W, src_cat, Wcat, gb);
  tcvt<<<dim3(64, 64, 3), 256, 0, stream>>>(thk, thq, thv, thkT, thqT, Wcat);

  gemm_proj<<<dim3(16, 32, 2), 256, 0, stream>>>(src_cat + 2048, thkT, thqT,
                                                 src_cat, trainT, testv);
  gemm_err<<<dim3(16, 32), 256, 0, stream>>>(src_cat, Wcat, bv, errT, gb);
  gemm_gw<<<dim3(16, 16, 2), 256, 0, stream>>>(errT, trainT, P0, P1);
  wnew_reduce<<<4096, 256, 0, stream>>>(P0, P1, W, lrw, WnewBf);
  gemm_out<<<dim3(16, 32), 256, 0, stream>>>(testv, WnewBf, bv, lrb, gb, out);
}

// Round 5
// 349.430 us; speedup vs baseline: 1.3554x; 1.2561x over previous
//
#include <hip/hip_runtime.h>
#include <hip/hip_bf16.h>
#include <hip/hip_fp8.h>
#include <stdint.h>

#define D_DIM 2048
#define B_TOK 4096
#define COEF (2.0f / 8388608.0f)   // 2/(B*D)

typedef __bf16 bf16x8 __attribute__((ext_vector_type(8)));
typedef float  f32x4  __attribute__((ext_vector_type(4)));
typedef int    i32x8  __attribute__((ext_vector_type(8)));
typedef unsigned short u16x8 __attribute__((ext_vector_type(8)));

__device__ __forceinline__ unsigned short f2bf(float f) {
  return __builtin_bit_cast(unsigned short, (__bf16)f);
}
__device__ __forceinline__ float bf2f(unsigned short u) {
  return (float)__builtin_bit_cast(__bf16, u);
}
__device__ __forceinline__ unsigned char f2f8(float f) {
  __hip_fp8_e4m3 v(f);            // OCP e4m3fn, RNE + satfinite
  return v.__x;
}

// async global->LDS, 16B per lane; LDS dest = wave-uniform base + lane*16
__device__ __forceinline__ void async16(const void* g, void* l) {
  __builtin_amdgcn_global_load_lds(
      (__attribute__((address_space(1))) void*)(g),
      (__attribute__((address_space(3))) void*)(l),
      16, 0, 0);
}

// ---------------------------------------------------------------------------
// BF16 core (unchanged, verified): C[128x128], BK=64, 2x2 waves, 4x4 of
// mfma_f32_16x16x32_bf16. XOR chunk swizzle for conflict-free ds_read_b128.
// ---------------------------------------------------------------------------
__device__ __forceinline__ void gemm_core(const unsigned short* __restrict__ Ablk,
                                          const unsigned short* __restrict__ Bblk,
                                          const int lda, const int ldb, const int KC,
                                          unsigned short* As, unsigned short* Bs,
                                          f32x4 acc[4][4]) {
  const int tid  = threadIdx.x;
  const int lane = tid & 63;
  const int wv   = tid >> 6;
  const int wm   = wv & 1, wn = wv >> 1;
  const int t    = lane & 15;
  const int quad = lane >> 4;
  const int lrow = lane >> 3;
  const int kq   = lane & 7;
  const int kqs  = kq ^ lrow;

  const int nk = KC >> 6;
  for (int kt = 0; kt < nk; ++kt) {
    const int k0 = kt << 6;
#pragma unroll
    for (int l = 0; l < 4; ++l) {
      const int seg = wv * 4 + l;
      const int r   = seg * 8 + lrow;
      async16(Ablk + (size_t)r * lda + k0 + kqs * 8, As + seg * 512);
      async16(Bblk + (size_t)r * ldb + k0 + kqs * 8, Bs + seg * 512);
    }
    __syncthreads();
#pragma unroll
    for (int s = 0; s < 2; ++s) {
      bf16x8 af[4], bfr[4];
#pragma unroll
      for (int i = 0; i < 4; ++i) {
        const int rm = wm * 64 + i * 16 + t;
        af[i]  = *(const bf16x8*)(As + rm * 64 + (((s << 2) + quad) ^ (rm & 7)) * 8);
        const int rn = wn * 64 + i * 16 + t;
        bfr[i] = *(const bf16x8*)(Bs + rn * 64 + (((s << 2) + quad) ^ (rn & 7)) * 8);
      }
#pragma unroll
      for (int i = 0; i < 4; ++i)
#pragma unroll
        for (int j = 0; j < 4; ++j)
          acc[i][j] = __builtin_amdgcn_mfma_f32_16x16x32_bf16(af[i], bfr[j], acc[i][j], 0, 0, 0);
    }
    __syncthreads();
  }
}

#define GEMM_PROLOGUE(AP, BP, LDAv, LDBv, KCv)                                 \
  __shared__ __align__(16) unsigned short As[128 * 64];                        \
  __shared__ __align__(16) unsigned short Bs[128 * 64];                        \
  const unsigned short* Ablk = (AP) + (size_t)blockIdx.y * 128 * (LDAv);       \
  const unsigned short* Bblk = (BP) + (size_t)blockIdx.x * 128 * (LDBv);       \
  f32x4 acc[4][4];                                                             \
  _Pragma("unroll") for (int i = 0; i < 4; ++i)                                \
  _Pragma("unroll") for (int j = 0; j < 4; ++j)                                \
      acc[i][j] = (f32x4){0.f, 0.f, 0.f, 0.f};                                 \
  gemm_core(Ablk, Bblk, (LDAv), (LDBv), (KCv), As, Bs, acc);                   \
  const int lane = threadIdx.x & 63;                                           \
  const int wv = threadIdx.x >> 6;                                             \
  const int wm = wv & 1, wn = wv >> 1;                                         \
  const int t = lane & 15, quad = lane >> 4;                                   \
  const int gm_base = blockIdx.y * 128 + wm * 64;                              \
  const int gn_base = blockIdx.x * 128 + wn * 64;

// ---------------------------------------------------------------------------
// FP8 MX core: C[128x128], BK=128 bytes, 2x2 waves, 4x4 of
// mfma_scale_f32_16x16x128_f8f6f4 (e4m3, scale=1.0 via e8m0 byte 127).
// A-frag: lane holds rows m=lane&15, K bytes [quad*32, quad*32+32) -> two b128
// reads from XOR-swizzled chunks (2q)^(r&7), (2q+1)^(r&7).
// ---------------------------------------------------------------------------
__device__ __forceinline__ void gemm_core_f8(const unsigned char* __restrict__ Ablk,
                                             const unsigned char* __restrict__ Bblk,
                                             const int lda, const int ldb, const int KC,
                                             unsigned char* As, unsigned char* Bs,
                                             f32x4 acc[4][4]) {
  const int tid  = threadIdx.x;
  const int lane = tid & 63;
  const int wv   = tid >> 6;
  const int wm   = wv & 1, wn = wv >> 1;
  const int t    = lane & 15;
  const int quad = lane >> 4;
  const int lrow = lane >> 3;
  const int kq   = lane & 7;
  const int kqs  = kq ^ lrow;

  const int nk = KC >> 7;
  for (int kt = 0; kt < nk; ++kt) {
    const int k0 = kt << 7;
#pragma unroll
    for (int l = 0; l < 4; ++l) {
      const int seg = wv * 4 + l;
      const int r   = seg * 8 + lrow;
      async16(Ablk + (size_t)r * lda + k0 + kqs * 16, As + seg * 1024);
      async16(Bblk + (size_t)r * ldb + k0 + kqs * 16, Bs + seg * 1024);
    }
    __syncthreads();
    i32x8 af[4];
#pragma unroll
    for (int i = 0; i < 4; ++i) {
      const int rm = wm * 64 + i * 16 + t;
      const unsigned char* base = As + rm * 128;
      const int x = rm & 7;
      const uint4 lo = *(const uint4*)(base + (((quad << 1)    ) ^ x) * 16);
      const uint4 hi = *(const uint4*)(base + (((quad << 1) | 1) ^ x) * 16);
      af[i] = (i32x8){(int)lo.x, (int)lo.y, (int)lo.z, (int)lo.w,
                      (int)hi.x, (int)hi.y, (int)hi.z, (int)hi.w};
    }
#pragma unroll
    for (int j = 0; j < 4; ++j) {
      const int rn = wn * 64 + j * 16 + t;
      const unsigned char* base = Bs + rn * 128;
      const int x = rn & 7;
      const uint4 lo = *(const uint4*)(base + (((quad << 1)    ) ^ x) * 16);
      const uint4 hi = *(const uint4*)(base + (((quad << 1) | 1) ^ x) * 16);
      const i32x8 bq = (i32x8){(int)lo.x, (int)lo.y, (int)lo.z, (int)lo.w,
                               (int)hi.x, (int)hi.y, (int)hi.z, (int)hi.w};
#pragma unroll
      for (int i = 0; i < 4; ++i)
        acc[i][j] = __builtin_amdgcn_mfma_scale_f32_16x16x128_f8f6f4(
            af[i], bq, acc[i][j], 0, 0, 0, 127, 0, 127);
    }
    __syncthreads();
  }
}

#define GEMM8_PROLOGUE(AP, BP, LDAv, LDBv, KCv)                                \
  __shared__ __align__(16) unsigned char As8[128 * 128];                       \
  __shared__ __align__(16) unsigned char Bs8[128 * 128];                       \
  const unsigned char* Ablk = (AP) + (size_t)blockIdx.y * 128 * (LDAv);        \
  const unsigned char* Bblk = (BP) + (size_t)blockIdx.x * 128 * (LDBv);        \
  f32x4 acc[4][4];                                                             \
  _Pragma("unroll") for (int i = 0; i < 4; ++i)                                \
  _Pragma("unroll") for (int j = 0; j < 4; ++j)                                \
      acc[i][j] = (f32x4){0.f, 0.f, 0.f, 0.f};                                 \
  gemm_core_f8(Ablk, Bblk, (LDAv), (LDBv), (KCv), As8, Bs8, acc);              \
  const int lane = threadIdx.x & 63;                                           \
  const int wv = threadIdx.x >> 6;                                             \
  const int wm = wv & 1, wn = wv >> 1;                                         \
  const int t = lane & 15, quad = lane >> 4;                                   \
  const int gm_base = blockIdx.y * 128 + wm * 64;                              \
  const int gn_base = blockIdx.x * 128 + wn * 64;

// GEMM-train (fp8): train = src @ thk^T. A = src_cat_f8 right half (lda 4096).
// Writes train fp8 into src_cat_f8 LEFT half + trainT8 (LDS-transposed).
__global__ __launch_bounds__(256) void gemm_train_f8(
    const unsigned char* __restrict__ srcA,     // src_cat_f8 + 2048
    const unsigned char* __restrict__ thkT8,    // ld 2048
    unsigned char* __restrict__ src_cat_f8,
    unsigned char* __restrict__ trainT8) {
  GEMM8_PROLOGUE(srcA, thkT8, 4096, 2048, 2048)
  unsigned char* scr = ((wv >> 1) ? Bs8 : As8) + (wv & 1) * 2304;  // 32 x 72 B
#pragma unroll
  for (int p = 0; p < 2; ++p) {
#pragma unroll
    for (int jl = 0; jl < 2; ++jl) {
      const int j = p * 2 + jl;
      const int gn = gn_base + j * 16 + t;
#pragma unroll
      for (int i = 0; i < 4; ++i) {
        const int gm0 = gm_base + i * 16 + quad * 4;
        uchar4 pk = make_uchar4(f2f8(acc[i][j][0]), f2f8(acc[i][j][1]),
                                f2f8(acc[i][j][2]), f2f8(acc[i][j][3]));
        src_cat_f8[(size_t)(gm0 + 0) * 4096 + gn] = pk.x;
        src_cat_f8[(size_t)(gm0 + 1) * 4096 + gn] = pk.y;
        src_cat_f8[(size_t)(gm0 + 2) * 4096 + gn] = pk.z;
        src_cat_f8[(size_t)(gm0 + 3) * 4096 + gn] = pk.w;
        *(uchar4*)(scr + (jl * 16 + t) * 72 + i * 16 + quad * 4) = pk;
      }
    }
    __syncthreads();
    const int row = lane >> 3, chunk = lane & 7;
#pragma unroll
    for (int q = 0; q < 4; ++q) {
      const int rr = q * 8 + row;
      const uint2 v = *(const uint2*)(scr + rr * 72 + chunk * 8);
      *(uint2*)(trainT8 + (size_t)(gn_base + p * 32 + rr) * B_TOK + gm_base + chunk * 8) = v;
    }
    __syncthreads();
  }
}

// GEMM-test (bf16): test = src @ thq^T -> testv (ld 2048)
__global__ __launch_bounds__(256) void gemm_test(
    const unsigned short* __restrict__ src_bf,
    const unsigned short* __restrict__ thqT,
    unsigned short* __restrict__ testv) {
  GEMM_PROLOGUE(src_bf, thqT, 2048, 2048, 2048)
#pragma unroll
  for (int i = 0; i < 4; ++i) {
#pragma unroll
    for (int j = 0; j < 4; ++j) {
      const int gm0 = gm_base + i * 16 + quad * 4;
      const int gn  = gn_base + j * 16 + t;
#pragma unroll
      for (int r = 0; r < 4; ++r)
        testv[(size_t)(gm0 + r) * D_DIM + gn] = f2bf(acc[i][j][r]);
    }
  }
}

// GEMM-err (fp8, K=4096): err = [train|src] @ [W | (thk-thv)^T]^T + b.
// Stored transposed errT8[D, B_TOK] fp8 + gb column sums.
__global__ __launch_bounds__(256) void gemm_err_f8(
    const unsigned char* __restrict__ src_cat_f8,
    const unsigned char* __restrict__ Wcat_f8,
    const float* __restrict__ bvec,
    unsigned char* __restrict__ errT8,
    float* __restrict__ gb) {
  GEMM8_PROLOGUE(src_cat_f8, Wcat_f8, 4096, 4096, 4096)
  unsigned char* scr = ((wv >> 1) ? Bs8 : As8) + (wv & 1) * 2304;
#pragma unroll
  for (int p = 0; p < 2; ++p) {
#pragma unroll
    for (int jl = 0; jl < 2; ++jl) {
      const int j = p * 2 + jl;
      const int gn = gn_base + j * 16 + t;
      const float bias = bvec[gn];
      float cs = 0.f;
#pragma unroll
      for (int i = 0; i < 4; ++i) {
        const float e0 = acc[i][j][0] + bias, e1 = acc[i][j][1] + bias;
        const float e2 = acc[i][j][2] + bias, e3 = acc[i][j][3] + bias;
        *(uchar4*)(scr + (jl * 16 + t) * 72 + i * 16 + quad * 4) =
            make_uchar4(f2f8(e0), f2f8(e1), f2f8(e2), f2f8(e3));
        cs += e0 + e1 + e2 + e3;
      }
      cs += __shfl_xor(cs, 16);
      cs += __shfl_xor(cs, 32);
      if (quad == 0) atomicAdd(&gb[gn], cs);
    }
    __syncthreads();
    const int row = lane >> 3, chunk = lane & 7;
#pragma unroll
    for (int q = 0; q < 4; ++q) {
      const int rr = q * 8 + row;
      const uint2 v = *(const uint2*)(scr + rr * 72 + chunk * 8);
      *(uint2*)(errT8 + (size_t)(gn_base + p * 32 + rr) * B_TOK + gm_base + chunk * 8) = v;
    }
    __syncthreads();
  }
}

// GEMM-gW (fp8, split-K=2): P_z = errT[:, z*2048:+2048] @ trainT[:, same]^T
__global__ __launch_bounds__(256) void gemm_gw_f8(
    const unsigned char* __restrict__ errT8,
    const unsigned char* __restrict__ trainT8,
    float* __restrict__ P0, float* __restrict__ P1) {
  const int z = blockIdx.z;
  const unsigned char* Abase = errT8 + z * 2048;
  const unsigned char* Bbase = trainT8 + z * 2048;
  GEMM8_PROLOGUE(Abase, Bbase, B_TOK, B_TOK, 2048)
  float* P = (z == 0) ? P0 : P1;
#pragma unroll
  for (int i = 0; i < 4; ++i) {
#pragma unroll
    for (int j = 0; j < 4; ++j) {
      const int gm0 = gm_base + i * 16 + quad * 4;
      const int gn  = gn_base + j * 16 + t;
#pragma unroll
      for (int r = 0; r < 4; ++r)
        P[(size_t)(gm0 + r) * D_DIM + gn] = acc[i][j][r];
    }
  }
}

// Reduce partials + SGD update: Wnew = bf16(W - lr_w * COEF * (P0+P1))
__global__ __launch_bounds__(256) void wnew_reduce(
    const float* __restrict__ P0, const float* __restrict__ P1,
    const float* __restrict__ W, const float* __restrict__ lr_w,
    unsigned short* __restrict__ Wnew) {
  const int i = blockIdx.x * 256 + threadIdx.x;
  const float4 p0 = ((const float4*)P0)[i];
  const float4 p1 = ((const float4*)P1)[i];
  const float4 w  = ((const float4*)W)[i];
  const float4 l  = ((const float4*)lr_w)[i];
  ((ushort4*)Wnew)[i] = make_ushort4(
      f2bf(w.x - l.x * (COEF * (p0.x + p1.x))),
      f2bf(w.y - l.y * (COEF * (p0.y + p1.y))),
      f2bf(w.z - l.z * (COEF * (p0.z + p1.z))),
      f2bf(w.w - l.w * (COEF * (p0.w + p1.w))));
}

// GEMM-out (bf16): z = test @ Wnew^T + b_new + test, b_new inline from gb
__global__ __launch_bounds__(256) void gemm_out(
    const unsigned short* __restrict__ testv,
    const unsigned short* __restrict__ Wnew,
    const float* __restrict__ bvec,
    const float* __restrict__ lr_b,
    const float* __restrict__ gb,
    float* __restrict__ out) {
  GEMM_PROLOGUE(testv, Wnew, 2048, 2048, 2048)
#pragma unroll
  for (int j = 0; j < 4; ++j) {
    const int gn = gn_base + j * 16 + t;
    const float bias = bvec[gn] - lr_b[gn] * (COEF * gb[gn]);
#pragma unroll
    for (int i = 0; i < 4; ++i) {
      const int gm0 = gm_base + i * 16 + quad * 4;
#pragma unroll
      for (int r = 0; r < 4; ++r) {
        const size_t idx = (size_t)(gm0 + r) * D_DIM + gn;
        out[idx] = acc[i][j][r] + bias + bf2f(testv[idx]);
      }
    }
  }
}

// Conversions: src -> src_bf (bf16, ld 2048) AND src_cat_f8 right half (fp8,
// ld 4096); W -> Wcat_f8 left half (fp8, ld 4096). First 512 threads zero gb.
__global__ __launch_bounds__(256) void cvt_all(const float* __restrict__ src,
                                               const float* __restrict__ W,
                                               unsigned short* __restrict__ src_bf,
                                               unsigned char* __restrict__ src_cat_f8,
                                               unsigned char* __restrict__ Wcat_f8,
                                               float* __restrict__ gb) {
  const int i = blockIdx.x * 256 + threadIdx.x;   // 0 .. 3145727
  if (i < 512) ((float4*)gb)[i] = (float4){0.f, 0.f, 0.f, 0.f};
  if (i < 2097152) {
    const int m = i >> 9, c = i & 511;
    const float4 v = ((const float4*)src)[i];
    ((ushort4*)src_bf)[i] = make_ushort4(f2bf(v.x), f2bf(v.y), f2bf(v.z), f2bf(v.w));
    *(uchar4*)(src_cat_f8 + (size_t)m * 4096 + 2048 + c * 4) =
        make_uchar4(f2f8(v.x), f2f8(v.y), f2f8(v.z), f2f8(v.w));
  } else {
    const int j = i - 2097152;
    const int n = j >> 9, c = j & 511;
    const float4 v = ((const float4*)W)[j];
    *(uchar4*)(Wcat_f8 + (size_t)n * 4096 + c * 4) =
        make_uchar4(f2f8(v.x), f2f8(v.y), f2f8(v.z), f2f8(v.w));
  }
}

// transpose+convert: z=0: thk^T -> thkT8 (fp8, ld 2048); z=1: thq^T -> thqT
// (bf16, ld 2048); z=2: (thk-thv)^T -> Wcat_f8 right half (fp8, ld 4096)
__global__ __launch_bounds__(256) void tcvt(
    const float* __restrict__ thk, const float* __restrict__ thq,
    const float* __restrict__ thv,
    unsigned char* __restrict__ thkT8, unsigned short* __restrict__ thqT,
    unsigned char* __restrict__ Wcat_f8) {
  __shared__ float tile[32][33];
  const int z = blockIdx.z;
  const int bx = blockIdx.x * 32, by = blockIdx.y * 32;
  const int tx = threadIdx.x & 31, ty = threadIdx.x >> 5;
#pragma unroll
  for (int l = 0; l < 4; ++l) {
    const int r = ty + l * 8;
    const size_t idx = (size_t)(by + r) * D_DIM + bx + tx;
    tile[r][tx] = (z == 0) ? thk[idx] : (z == 1) ? thq[idx] : (thk[idx] - thv[idx]);
  }
  __syncthreads();
#pragma unroll
  for (int l = 0; l < 4; ++l) {
    const int r = ty + l * 8;
    if (z == 0)
      thkT8[(size_t)(bx + r) * 2048 + by + tx] = f2f8(tile[tx][r]);
    else if (z == 1)
      thqT[(size_t)(bx + r) * 2048 + by + tx] = f2bf(tile[tx][r]);
    else
      Wcat_f8[(size_t)(bx + r) * 4096 + 2048 + by + tx] = f2f8(tile[tx][r]);
  }
}

extern "C" void kernel_launch(void* const* d_in, const int* in_sizes, int n_in,
                              void* d_out, int out_size, void* d_ws, size_t ws_size,
                              hipStream_t stream) {
  const float* src = (const float*)d_in[0];
  const float* thk = (const float*)d_in[1];
  const float* thq = (const float*)d_in[2];
  const float* thv = (const float*)d_in[3];
  const float* W   = (const float*)d_in[4];
  const float* bv  = (const float*)d_in[5];
  const float* lrw = (const float*)d_in[6];
  const float* lrb = (const float*)d_in[7];
  float* out = (float*)d_out;

  char* ws = (char*)d_ws;
  const size_t MB = 1024 * 1024;
  unsigned short* src_bf     = (unsigned short*)(ws + 0);        // 16 MB bf16 [4096x2048]
  unsigned char*  src_cat_f8 = (unsigned char*)(ws + 16 * MB);   // 16 MB fp8 [4096x4096] (train|src)
  unsigned char*  Wcat_f8    = (unsigned char*)(ws + 32 * MB);   //  8 MB fp8 [2048x4096] (W | thk-thv ^T)
  unsigned char*  thkT8      = (unsigned char*)(ws + 40 * MB);   //  4 MB fp8
  unsigned short* thqT       = (unsigned short*)(ws + 44 * MB);  //  8 MB bf16
  unsigned char*  trainT8    = (unsigned char*)(ws + 52 * MB);   //  8 MB fp8 [2048x4096]
  unsigned short* testv      = (unsigned short*)(ws + 60 * MB);  // 16 MB bf16
  unsigned char*  errT8      = (unsigned char*)(ws + 76 * MB);   //  8 MB fp8 [2048x4096]
  unsigned short* WnewBf     = (unsigned short*)(ws + 84 * MB);  //  8 MB bf16
  float*          P0         = (float*)(ws + 92 * MB);           // 16 MB f32
  float*          P1         = (float*)(ws + 108 * MB);          // 16 MB f32
  float*          gb         = (float*)(ws + 124 * MB);          //  8 KB

  cvt_all<<<12288, 256, 0, stream>>>(src, W, src_bf, src_cat_f8, Wcat_f8, gb);
  tcvt<<<dim3(64, 64, 3), 256, 0, stream>>>(thk, thq, thv, thkT8, thqT, Wcat_f8);

  gemm_train_f8<<<dim3(16, 32), 256, 0, stream>>>(src_cat_f8 + 2048, thkT8,
                                                  src_cat_f8, trainT8);
  gemm_test<<<dim3(16, 32), 256, 0, stream>>>(src_bf, thqT, testv);
  gemm_err_f8<<<dim3(16, 32), 256, 0, stream>>>(src_cat_f8, Wcat_f8, bv, errT8, gb);
  gemm_gw_f8<<<dim3(16, 16, 2), 256, 0, stream>>>(errT8, trainT8, P0, P1);
  wnew_reduce<<<4096, 256, 0, stream>>>(P0, P1, W, lrw, WnewBf);
  gemm_out<<<dim3(16, 32), 256, 0, stream>>>(testv, WnewBf, bv, lrb, gb, out);
}